// Round 4
// baseline (385.595 us; speedup 1.0000x reference)
//
#include <hip/hip_runtime.h>
#include <stdint.h>
#include <stddef.h>

#define IN_F  4096
#define OUT_F 4096
#define BATCH 8192

typedef _Float16 f16;
typedef _Float16 f16x4 __attribute__((ext_vector_type(4)));
typedef _Float16 f16x8 __attribute__((ext_vector_type(8)));
typedef float    f32x4 __attribute__((ext_vector_type(4)));

#define VMWAIT(n) asm volatile("s_waitcnt vmcnt(" #n ")" ::: "memory")
// one barrier section per phase: drain own ds_reads, then join
#define PHASE_END() do { \
    asm volatile("s_waitcnt lgkmcnt(0)" ::: "memory"); \
    __builtin_amdgcn_s_barrier(); \
    asm volatile("" ::: "memory"); \
} while (0)

// ---------------- helpers ----------------

__device__ __forceinline__ float softplus_f(float x) {
    return fmaxf(x, 0.0f) + log1pf(__expf(-fabsf(x)));
}

__device__ __forceinline__ void block_reduce_atomic(float v, float* dst) {
    #pragma unroll
    for (int off = 32; off > 0; off >>= 1) v += __shfl_down(v, off, 64);
    __shared__ float parts[16];
    const int lane = threadIdx.x & 63, wave = threadIdx.x >> 6;
    if (lane == 0) parts[wave] = v;
    __syncthreads();
    if (threadIdx.x == 0) {
        float s = 0.0f;
        const int nw = blockDim.x >> 6;
        for (int i = 0; i < nw; ++i) s += parts[i];
        atomicAdd(dst, s);
    }
}

__device__ __forceinline__ void async16(void* lds, const void* g) {
    __builtin_amdgcn_global_load_lds(
        (const __attribute__((address_space(1))) void*)g,
        (__attribute__((address_space(3))) void*)lds,
        16, 0, 0);
}

// ---------------- prep kernels (unchanged, verified) ----------------

__global__ __launch_bounds__(256) void prep_w_kernel(
    const float4* __restrict__ mu4, const float4* __restrict__ rho4,
    const float4* __restrict__ nz4, f16x4* __restrict__ W4,
    float* __restrict__ kl_accum, int n4)
{
    float kl = 0.0f;
    const int stride = gridDim.x * blockDim.x;
    for (int i = blockIdx.x * blockDim.x + threadIdx.x; i < n4; i += stride) {
        const float4 m = mu4[i], r = rho4[i], z = nz4[i];
        const float mm[4] = {m.x, m.y, m.z, m.w};
        const float rr[4] = {r.x, r.y, r.z, r.w};
        const float zz[4] = {z.x, z.y, z.z, z.w};
        f16x4 w;
        #pragma unroll
        for (int c = 0; c < 4; ++c) {
            const float s = softplus_f(rr[c]);
            w[c] = (f16)(mm[c] + s * zz[c]);
            kl += 2.0f * __logf(s) + 1.0f / (s * s) + mm[c] * mm[c] - 1.0f;
        }
        W4[i] = w;
    }
    block_reduce_atomic(0.5f * kl, kl_accum);
}

__global__ __launch_bounds__(256) void prep_small_kernel(
    const float* __restrict__ bias_mu, const float* __restrict__ bias_rho,
    const float* __restrict__ alpha,   const float* __restrict__ beta,
    const float* __restrict__ bias_nz,
    float* __restrict__ ascale, float* __restrict__ bias,
    float* __restrict__ kl_accum)
{
    const int i = blockIdx.x * blockDim.x + threadIdx.x;
    float kl = 0.0f;
    if (i < IN_F) {
        const float sa = softplus_f(alpha[i]);
        const float sb = softplus_f(beta[i]);
        ascale[i] = sa * sb;
        kl += sa + sb - __logf(sa) - __logf(sb);
    }
    if (i < OUT_F) {
        const float s = softplus_f(bias_rho[i]);
        const float bm = bias_mu[i];
        bias[i] = bm + s * bias_nz[i];
        kl += 0.5f * (2.0f * __logf(s) + 1.0f / (s * s) + bm * bm - 1.0f);
    }
    block_reduce_atomic(kl, kl_accum);
}

__global__ __launch_bounds__(256) void prep_x_kernel(
    const float4* __restrict__ x4, const float4* __restrict__ u4,
    const float4* __restrict__ as4, f16x4* __restrict__ xd4, int n4)
{
    constexpr int C4 = IN_F / 4;
    const int stride = gridDim.x * blockDim.x;
    for (int i = blockIdx.x * blockDim.x + threadIdx.x; i < n4; i += stride) {
        const float4 xv = x4[i];
        const float4 uv = u4[i];
        const float4 av = as4[i & (C4 - 1)];
        f16x4 o;
        const float inv_keep = 1.0f / 0.9f;
        o[0] = (f16)((uv.x < 0.9f) ? xv.x * inv_keep * av.x : 0.0f);
        o[1] = (f16)((uv.y < 0.9f) ? xv.y * inv_keep * av.y : 0.0f);
        o[2] = (f16)((uv.z < 0.9f) ? xv.z * inv_keep * av.z : 0.0f);
        o[3] = (f16)((uv.w < 0.9f) ? xv.w * inv_keep * av.w : 0.0f);
        xd4[i] = o;
    }
}

// ---------------- GEMM: 256x256 tile, BK=64, fused-phase counted-vmcnt ----------------
// C[M][N] = A[M][K] * B[N][K]^T + bias.  8 waves (2Mx4N), interleaved wave tiling.
// ONE barrier section per phase: {stage, ds_read(next operands), MFMA(deferred
// operands, read >=1 phase earlier), lgkmcnt(0), barrier} -> LDS-read pipe and
// MFMA pipe overlap inside the section instead of serializing across barriers.
//   P0: stage A1(t+1) | read a_lo(t) | mfma q10(t-1)
//   P1: stage A0(t+2) | read b_lo(t) | mfma q11(t-1)
//   P2: stage B0(t+2) | read b_hi(t) | mfma q00(t)
//   P3: stage B1(t+2) | read a_hi(t) | mfma q01(t) | vmcnt(6)
// WAR safety: a region is staged only in the phase AFTER its last ds_read was
// issued AND drained (lgkmcnt(0) precedes every barrier); stage sits at phase
// start, right after that barrier. vmcnt FIFO: per tile issues {A1(t+1),
// A0(t+2), B0(t+2), B1(t+2)}; wait-6 at tile end drains exactly tile t+1.

#define QMFMA(MH, NH, AF, BF) do { \
    _Pragma("unroll") for (int mm_ = 0; mm_ < 4; ++mm_) \
    _Pragma("unroll") for (int nn_ = 0; nn_ < 2; ++nn_) \
    _Pragma("unroll") for (int ks_ = 0; ks_ < 2; ++ks_) \
        acc[(MH)*4+mm_][(NH)*2+nn_] = __builtin_amdgcn_mfma_f32_16x16x32_f16( \
            AF[mm_][ks_], BF[nn_][ks_], acc[(MH)*4+mm_][(NH)*2+nn_], 0, 0, 0); \
} while (0)

__global__ __launch_bounds__(512, 2) void gemm_kernel(
    const f16* __restrict__ A, const f16* __restrict__ B,
    const float* __restrict__ bias, float* __restrict__ C)
{
    constexpr int K = IN_F, N = OUT_F;
    constexpr int BK = 64, NT = K / BK; // 64 K-tiles

    extern __shared__ f16x8 smem_raw[];
    char* const smem = (char*)smem_raw;
    char* const sA = smem;          // [2][256][64] f16, unit-swizzled
    char* const sB = smem + 65536;  // [2][256][64] f16

    const int tid  = threadIdx.x;
    const int lane = tid & 63, wave = tid >> 6;
    const int wr = wave >> 2, wc = wave & 3;   // 2 x 4 waves
    const int fr = lane & 15, fq = lane >> 4;

    // XCD-aware block swizzle (512 wgs, 512%8==0 -> bijective)
    int bid = blockIdx.x;
    const int nbn = N / 256; // 16
    bid = (bid & 7) * 64 + (bid >> 3);
    const int row0 = (bid / nbn) * 256, col0 = (bid % nbn) * 256;

    // staging source (pre-swizzled so linear gload_lds dest + swizzled read match)
    const int srow  = tid >> 3;
    const int sunit = (tid & 7) ^ (srow & 7);
    const f16* gA = A + (size_t)(row0 + srow) * K + sunit * 8;
    const f16* gB = B + (size_t)(col0 + srow) * K + sunit * 8;
    const int sdst = tid * 16;

#define STA(T, H, J) async16(sA + ((T) & 1) * 32768 + (H) * 16384 + (J) * 8192 + sdst, \
                             gA + (size_t)((H) * 128 + (J) * 64) * K + (T) * 64)
#define STB(T, H, J) async16(sB + ((T) & 1) * 32768 + (H) * 16384 + (J) * 8192 + sdst, \
                             gB + (size_t)((H) * 128 + (J) * 64) * K + (T) * 64)

    // ds_read bases: byte = row*128 + (((fq+4*ks) ^ (row&7))<<4)
    const int swz0 = (fq ^ (fr & 7)) << 4;
    const int arow = (wr * 16 + fr) * 128;
    const int brow = (wc * 16 + fr) * 128;

    f32x4 acc[8][4] = {};
    f16x8 a_lo[4][2], a_hi[4][2], b_lo[2][2], b_hi[2][2];

    // prologue: tile0 in consumption order (A0,B0,B1,A1) + tile1 A0,B0,B1
    STA(0,0,0); STA(0,0,1); STB(0,0,0); STB(0,0,1);
    STB(0,1,0); STB(0,1,1); STA(0,1,0); STA(0,1,1);
    STA(1,0,0); STA(1,0,1); STB(1,0,0); STB(1,0,1);
    STB(1,1,0); STB(1,1,1);
    VMWAIT(6);   // tile0 landed; tile1 A0,B0,B1 in flight
    __builtin_amdgcn_s_barrier();
    asm volatile("" ::: "memory");

    for (int t = 0; t < NT; ++t) {
        const int ab = (t & 1) * 32768;
        const int a0 = ab + arow + swz0;
        const int b0 = ab + brow + swz0;

        // ---- P0: stage A1(t+1) | read a_lo(t) | mfma q10(t-1)
        if (t + 1 < NT) { STA(t+1, 1, 0); STA(t+1, 1, 1); }
        #pragma unroll
        for (int mm = 0; mm < 4; ++mm)
            #pragma unroll
            for (int ks = 0; ks < 2; ++ks)
                a_lo[mm][ks] = *(const f16x8*)(sA + ((a0 ^ (ks << 6)) + mm * 4096));
        if (t > 0) {
            __builtin_amdgcn_s_setprio(1);
            QMFMA(1, 0, a_hi, b_lo);
            __builtin_amdgcn_s_setprio(0);
        }
        PHASE_END();

        // ---- P1: stage A0(t+2) | read b_lo(t) | mfma q11(t-1)
        if (t + 2 < NT) { STA(t+2, 0, 0); STA(t+2, 0, 1); }
        #pragma unroll
        for (int nn = 0; nn < 2; ++nn)
            #pragma unroll
            for (int ks = 0; ks < 2; ++ks)
                b_lo[nn][ks] = *(const f16x8*)(sB + ((b0 ^ (ks << 6)) + nn * 8192));
        if (t > 0) {
            __builtin_amdgcn_s_setprio(1);
            QMFMA(1, 1, a_hi, b_hi);
            __builtin_amdgcn_s_setprio(0);
        }
        PHASE_END();

        // ---- P2: stage B0(t+2) | read b_hi(t) | mfma q00(t)
        if (t + 2 < NT) { STB(t+2, 0, 0); STB(t+2, 0, 1); }
        #pragma unroll
        for (int nn = 0; nn < 2; ++nn)
            #pragma unroll
            for (int ks = 0; ks < 2; ++ks)
                b_hi[nn][ks] = *(const f16x8*)(sB + ((b0 ^ (ks << 6)) + 16384 + nn * 8192));
        __builtin_amdgcn_s_setprio(1);
        QMFMA(0, 0, a_lo, b_lo);
        __builtin_amdgcn_s_setprio(0);
        PHASE_END();

        // ---- P3: stage B1(t+2) | read a_hi(t) | mfma q01(t) | boundary vmcnt
        if (t + 2 < NT) { STB(t+2, 1, 0); STB(t+2, 1, 1); }
        #pragma unroll
        for (int mm = 0; mm < 4; ++mm)
            #pragma unroll
            for (int ks = 0; ks < 2; ++ks)
                a_hi[mm][ks] = *(const f16x8*)(sA + ((a0 ^ (ks << 6)) + 16384 + mm * 4096));
        __builtin_amdgcn_s_setprio(1);
        QMFMA(0, 1, a_lo, b_hi);
        __builtin_amdgcn_s_setprio(0);
        if (t < NT - 2) { VMWAIT(6); } else { VMWAIT(0); }
        PHASE_END();
    }
    // deferred quadrants of tile NT-1
    QMFMA(1, 0, a_hi, b_lo);
    QMFMA(1, 1, a_hi, b_hi);

    // epilogue
    #pragma unroll
    for (int n = 0; n < 4; ++n) {
        const int col = col0 + n * 64 + wc * 16 + fr;
        const float bv = bias[col];
        #pragma unroll
        for (int m = 0; m < 8; ++m) {
            const int row = row0 + m * 32 + wr * 16 + fq * 4;
            #pragma unroll
            for (int r = 0; r < 4; ++r)
                C[(size_t)(row + r) * N + col] = acc[m][n][r] + bv;
        }
    }
#undef STA
#undef STB
}

__global__ void finalize_kernel(const float* __restrict__ kl, float* __restrict__ dst) {
    *dst = *kl;
}

// ---------------- launch ----------------

extern "C" void kernel_launch(void* const* d_in, const int* in_sizes, int n_in,
                              void* d_out, int out_size, void* d_ws, size_t ws_size,
                              hipStream_t stream)
{
    const float* x      = (const float*)d_in[0];
    const float* wmu    = (const float*)d_in[1];
    const float* wrho   = (const float*)d_in[2];
    const float* bmu    = (const float*)d_in[3];
    const float* brho   = (const float*)d_in[4];
    const float* alpha  = (const float*)d_in[5];
    const float* beta   = (const float*)d_in[6];
    const float* wnz    = (const float*)d_in[7];
    const float* bnz    = (const float*)d_in[8];
    const float* du     = (const float*)d_in[9];

    char* ws = (char*)d_ws;
    f16*   W      = (f16*)(ws);
    f16*   XD     = (f16*)(ws + 33554432);
    float* ascale = (float*)(ws + 100663296);
    float* biasv  = (float*)(ws + 100679680);
    float* klacc  = (float*)(ws + 100696064);

    float* out = (float*)d_out;

    hipMemsetAsync(klacc, 0, sizeof(float), stream);

    prep_small_kernel<<<16, 256, 0, stream>>>(bmu, brho, alpha, beta, bnz,
                                              ascale, biasv, klacc);
    prep_w_kernel<<<2048, 256, 0, stream>>>(
        (const float4*)wmu, (const float4*)wrho, (const float4*)wnz,
        (f16x4*)W, klacc, OUT_F * IN_F / 4);
    prep_x_kernel<<<2048, 256, 0, stream>>>(
        (const float4*)x, (const float4*)du, (const float4*)ascale,
        (f16x4*)XD, BATCH * IN_F / 4);

    hipFuncSetAttribute((const void*)gemm_kernel,
                        hipFuncAttributeMaxDynamicSharedMemorySize, 131072);
    gemm_kernel<<<512, 512, 131072, stream>>>(XD, W, biasv, out);

    finalize_kernel<<<1, 1, 0, stream>>>(klacc, out + (size_t)BATCH * OUT_F);
}

// Round 7
// 368.751 us; speedup vs baseline: 1.0457x; 1.0457x over previous
//
#include <hip/hip_runtime.h>
#include <stdint.h>
#include <stddef.h>

#define IN_F  4096
#define OUT_F 4096
#define BATCH 8192

typedef _Float16 f16;
typedef _Float16 f16x4 __attribute__((ext_vector_type(4)));
typedef _Float16 f16x8 __attribute__((ext_vector_type(8)));
typedef float    f32x4 __attribute__((ext_vector_type(4)));

#define VMWAIT(n) asm volatile("s_waitcnt vmcnt(" #n ")" ::: "memory")
#define LGKM0()   asm volatile("s_waitcnt lgkmcnt(0)" ::: "memory")
#define BAR() do { asm volatile("" ::: "memory"); __builtin_amdgcn_s_barrier(); asm volatile("" ::: "memory"); } while (0)

// ---------------- helpers ----------------

__device__ __forceinline__ float softplus_f(float x) {
    return fmaxf(x, 0.0f) + log1pf(__expf(-fabsf(x)));
}

__device__ __forceinline__ void block_reduce_atomic(float v, float* dst) {
    #pragma unroll
    for (int off = 32; off > 0; off >>= 1) v += __shfl_down(v, off, 64);
    __shared__ float parts[16];
    const int lane = threadIdx.x & 63, wave = threadIdx.x >> 6;
    if (lane == 0) parts[wave] = v;
    __syncthreads();
    if (threadIdx.x == 0) {
        float s = 0.0f;
        const int nw = blockDim.x >> 6;
        for (int i = 0; i < nw; ++i) s += parts[i];
        atomicAdd(dst, s);
    }
}

__device__ __forceinline__ void async16(void* lds, const void* g) {
    __builtin_amdgcn_global_load_lds(
        (const __attribute__((address_space(1))) void*)g,
        (__attribute__((address_space(3))) void*)lds,
        16, 0, 0);
}

// ---------------- prep kernels (unchanged, verified) ----------------

__global__ __launch_bounds__(256) void prep_w_kernel(
    const float4* __restrict__ mu4, const float4* __restrict__ rho4,
    const float4* __restrict__ nz4, f16x4* __restrict__ W4,
    float* __restrict__ kl_accum, int n4)
{
    float kl = 0.0f;
    const int stride = gridDim.x * blockDim.x;
    for (int i = blockIdx.x * blockDim.x + threadIdx.x; i < n4; i += stride) {
        const float4 m = mu4[i], r = rho4[i], z = nz4[i];
        const float mm[4] = {m.x, m.y, m.z, m.w};
        const float rr[4] = {r.x, r.y, r.z, r.w};
        const float zz[4] = {z.x, z.y, z.z, z.w};
        f16x4 w;
        #pragma unroll
        for (int c = 0; c < 4; ++c) {
            const float s = softplus_f(rr[c]);
            w[c] = (f16)(mm[c] + s * zz[c]);
            kl += 2.0f * __logf(s) + 1.0f / (s * s) + mm[c] * mm[c] - 1.0f;
        }
        W4[i] = w;
    }
    block_reduce_atomic(0.5f * kl, kl_accum);
}

__global__ __launch_bounds__(256) void prep_small_kernel(
    const float* __restrict__ bias_mu, const float* __restrict__ bias_rho,
    const float* __restrict__ alpha,   const float* __restrict__ beta,
    const float* __restrict__ bias_nz,
    float* __restrict__ ascale, float* __restrict__ bias,
    float* __restrict__ kl_accum)
{
    const int i = blockIdx.x * blockDim.x + threadIdx.x;
    float kl = 0.0f;
    if (i < IN_F) {
        const float sa = softplus_f(alpha[i]);
        const float sb = softplus_f(beta[i]);
        ascale[i] = sa * sb;
        kl += sa + sb - __logf(sa) - __logf(sb);
    }
    if (i < OUT_F) {
        const float s = softplus_f(bias_rho[i]);
        const float bm = bias_mu[i];
        bias[i] = bm + s * bias_nz[i];
        kl += 0.5f * (2.0f * __logf(s) + 1.0f / (s * s) + bm * bm - 1.0f);
    }
    block_reduce_atomic(kl, kl_accum);
}

__global__ __launch_bounds__(256) void prep_x_kernel(
    const float4* __restrict__ x4, const float4* __restrict__ u4,
    const float4* __restrict__ as4, f16x4* __restrict__ xd4, int n4)
{
    constexpr int C4 = IN_F / 4;
    const int stride = gridDim.x * blockDim.x;
    for (int i = blockIdx.x * blockDim.x + threadIdx.x; i < n4; i += stride) {
        const float4 xv = x4[i];
        const float4 uv = u4[i];
        const float4 av = as4[i & (C4 - 1)];
        f16x4 o;
        const float inv_keep = 1.0f / 0.9f;
        o[0] = (f16)((uv.x < 0.9f) ? xv.x * inv_keep * av.x : 0.0f);
        o[1] = (f16)((uv.y < 0.9f) ? xv.y * inv_keep * av.y : 0.0f);
        o[2] = (f16)((uv.z < 0.9f) ? xv.z * inv_keep * av.z : 0.0f);
        o[3] = (f16)((uv.w < 0.9f) ? xv.w * inv_keep * av.w : 0.0f);
        xd4[i] = o;
    }
}

// ---------------- GEMM: 256x256, BK=64, m201-faithful single-barrier phases --------
// FENCE RULE (R4/R5 NaN root cause): vmcnt is PER-WAVE; LDS regions are staged
// cooperatively by all waves. A region is readable only after every wave's
// VMWAIT *followed by* a barrier. VMWAIT must precede the barrier, never follow.
//
// Phases of tile t (buf bt = t&1; MFMA consumes same-phase reads via post-bar lgkm0):
//   P0: read a_lo(t)[8] b_lo(t)[4] | stage A1(t+1),A0(t+1) | lgkm(8) | BAR | lgkm0 | q00
//   P1: read b_hi(t)[4]            |                        BAR | lgkm0 | q01
//   P2: read a_hi(t)[8]            | stage B0(t+2)        | BAR | lgkm0 | q10
//   P3:                            | stage B1(t+2) | VMWAIT(4) | BAR |    q11
// vmcnt chain (2-load units): {A1(t+1),A0(t+1)}@P0, B0(t+2)@P2, B1(t+2)@P3.
// VMWAIT(4)@P3 leaves {B0(t+2),B1(t+2)} -> drains everything tile t+1 reads. Formal.
// LDS WAR: every region's stage-issue is >=1 full barrier after its read-drain
// (reads drain at lgkm0 before that wave's next barrier). Formal.
// Tail: stages wrap mod NT (uniform counts; wrapped data never consumed, same
// WAR gaps); VMWAIT(0) before epilogue.

#define QMFMA(MH, NH, AF, BF) do { \
    _Pragma("unroll") for (int mm_ = 0; mm_ < 4; ++mm_) \
    _Pragma("unroll") for (int nn_ = 0; nn_ < 2; ++nn_) \
    _Pragma("unroll") for (int ks_ = 0; ks_ < 2; ++ks_) \
        acc[(MH)*4+mm_][(NH)*2+nn_] = __builtin_amdgcn_mfma_f32_16x16x32_f16( \
            AF[mm_][ks_], BF[nn_][ks_], acc[(MH)*4+mm_][(NH)*2+nn_], 0, 0, 0); \
} while (0)

__global__ __launch_bounds__(512, 2) void gemm_kernel(
    const f16* __restrict__ A, const f16* __restrict__ B,
    const float* __restrict__ bias, float* __restrict__ C)
{
    constexpr int K = IN_F, N = OUT_F;
    constexpr int BK = 64, NT = K / BK; // 64 K-tiles

    extern __shared__ f16x8 smem_raw[];
    char* const smem = (char*)smem_raw;
    char* const sA = smem;          // [2 buf][2 half][128][64] f16, unit-swizzled
    char* const sB = smem + 65536;

    const int tid  = threadIdx.x;
    const int lane = tid & 63, wave = tid >> 6;
    const int wr = wave >> 2, wc = wave & 3;   // 2 x 4 waves
    const int fr = lane & 15, fq = lane >> 4;

    int bid = blockIdx.x;
    const int nbn = N / 256; // 16
    bid = (bid & 7) * 64 + (bid >> 3); // XCD swizzle, 512%8==0 bijective
    const int row0 = (bid / nbn) * 256, col0 = (bid % nbn) * 256;

    // staging source (pre-swizzled; linear gload_lds dest + swizzled ds_read)
    const int srow  = tid >> 3;
    const int sunit = (tid & 7) ^ (srow & 7);
    const f16* gA = A + (size_t)(row0 + srow) * K + sunit * 8;
    const f16* gB = B + (size_t)(col0 + srow) * K + sunit * 8;
    const int sdst = tid * 16;

#define STA(T, H, J) async16(sA + ((T) & 1) * 32768 + (H) * 16384 + (J) * 8192 + sdst, \
                             gA + (size_t)((H) * 128 + (J) * 64) * K + (T) * 64)
#define STB(T, H, J) async16(sB + ((T) & 1) * 32768 + (H) * 16384 + (J) * 8192 + sdst, \
                             gB + (size_t)((H) * 128 + (J) * 64) * K + (T) * 64)

    const int swz0 = (fq ^ (fr & 7)) << 4;
    const int arow = (wr * 16 + fr) * 128;
    const int brow = (wc * 16 + fr) * 128;

#define READ_ALO(buf) do { _Pragma("unroll") for (int mm = 0; mm < 4; ++mm) \
    _Pragma("unroll") for (int ks = 0; ks < 2; ++ks) \
        a_lo[mm][ks] = *(const f16x8*)(sA + (buf) + (((arow + mm * 4096) + swz0) ^ (ks << 6))); } while (0)
#define READ_AHI(buf) do { _Pragma("unroll") for (int mm = 0; mm < 4; ++mm) \
    _Pragma("unroll") for (int ks = 0; ks < 2; ++ks) \
        a_hi[mm][ks] = *(const f16x8*)(sA + (buf) + 16384 + (((arow + mm * 4096) + swz0) ^ (ks << 6))); } while (0)
#define READ_BLO(buf) do { _Pragma("unroll") for (int nn = 0; nn < 2; ++nn) \
    _Pragma("unroll") for (int ks = 0; ks < 2; ++ks) \
        b_lo[nn][ks] = *(const f16x8*)(sB + (buf) + (((brow + nn * 8192) + swz0) ^ (ks << 6))); } while (0)
#define READ_BHI(buf) do { _Pragma("unroll") for (int nn = 0; nn < 2; ++nn) \
    _Pragma("unroll") for (int ks = 0; ks < 2; ++ks) \
        b_hi[nn][ks] = *(const f16x8*)(sB + (buf) + 16384 + (((brow + nn * 8192) + swz0) ^ (ks << 6))); } while (0)

    f32x4 acc[8][4] = {};
    f16x8 a_lo[4][2], a_hi[4][2], b_lo[2][2], b_hi[2][2];

    // prologue: B0(0),B1(0),A1(0),A0(0),B0(1),B1(1) then VMWAIT(4)+BAR.
    // Leaves {B0(1),B1(1)} outstanding = exact steady-state P3-exit invariant.
    STB(0,0,0); STB(0,0,1);
    STB(0,1,0); STB(0,1,1);
    STA(0,1,0); STA(0,1,1);
    STA(0,0,0); STA(0,0,1);
    STB(1,0,0); STB(1,0,1);
    STB(1,1,0); STB(1,1,1);
    VMWAIT(4);
    BAR();

    for (int t = 0; t < NT; ++t) {
        const int bt  = (t & 1) * 32768;
        const int tp1 = (t + 1) & (NT - 1);
        const int tp2 = (t + 2) & (NT - 1);

        // ---- P0: read a_lo(t), b_lo(t) | stage A1(t+1), A0(t+1) | q00
        READ_ALO(bt);
        READ_BLO(bt);
        STA(tp1, 1, 0); STA(tp1, 1, 1);
        STA(tp1, 0, 0); STA(tp1, 0, 1);
        asm volatile("s_waitcnt lgkmcnt(8)" ::: "memory");
        BAR();
        LGKM0();
        __builtin_amdgcn_s_setprio(1);
        QMFMA(0, 0, a_lo, b_lo);
        __builtin_amdgcn_s_setprio(0);

        // ---- P1: read b_hi(t) | q01
        READ_BHI(bt);
        BAR();
        LGKM0();
        __builtin_amdgcn_s_setprio(1);
        QMFMA(0, 1, a_lo, b_hi);
        __builtin_amdgcn_s_setprio(0);

        // ---- P2: read a_hi(t) | stage B0(t+2) | q10
        READ_AHI(bt);
        STB(tp2, 0, 0); STB(tp2, 0, 1);
        BAR();
        LGKM0();
        __builtin_amdgcn_s_setprio(1);
        QMFMA(1, 0, a_hi, b_lo);
        __builtin_amdgcn_s_setprio(0);

        // ---- P3: stage B1(t+2) | VMWAIT(4) -> BAR (cross-wave staging fence) | q11
        STB(tp2, 1, 0); STB(tp2, 1, 1);
        VMWAIT(4);
        BAR();
        __builtin_amdgcn_s_setprio(1);
        QMFMA(1, 1, a_hi, b_hi);
        __builtin_amdgcn_s_setprio(0);
    }
    VMWAIT(0);   // drain dangling wrapped stages before epilogue

    // epilogue
    #pragma unroll
    for (int n = 0; n < 4; ++n) {
        const int col = col0 + n * 64 + wc * 16 + fr;
        const float bv = bias[col];
        #pragma unroll
        for (int m = 0; m < 8; ++m) {
            const int row = row0 + m * 32 + wr * 16 + fq * 4;
            #pragma unroll
            for (int r = 0; r < 4; ++r)
                C[(size_t)(row + r) * N + col] = acc[m][n][r] + bv;
        }
    }
#undef STA
#undef STB
}

__global__ void finalize_kernel(const float* __restrict__ kl, float* __restrict__ dst) {
    *dst = *kl;
}

// ---------------- launch ----------------

extern "C" void kernel_launch(void* const* d_in, const int* in_sizes, int n_in,
                              void* d_out, int out_size, void* d_ws, size_t ws_size,
                              hipStream_t stream)
{
    const float* x      = (const float*)d_in[0];
    const float* wmu    = (const float*)d_in[1];
    const float* wrho   = (const float*)d_in[2];
    const float* bmu    = (const float*)d_in[3];
    const float* brho   = (const float*)d_in[4];
    const float* alpha  = (const float*)d_in[5];
    const float* beta   = (const float*)d_in[6];
    const float* wnz    = (const float*)d_in[7];
    const float* bnz    = (const float*)d_in[8];
    const float* du     = (const float*)d_in[9];

    char* ws = (char*)d_ws;
    f16*   W      = (f16*)(ws);
    f16*   XD     = (f16*)(ws + 33554432);
    float* ascale = (float*)(ws + 100663296);
    float* biasv  = (float*)(ws + 100679680);
    float* klacc  = (float*)(ws + 100696064);

    float* out = (float*)d_out;

    hipMemsetAsync(klacc, 0, sizeof(float), stream);

    prep_small_kernel<<<16, 256, 0, stream>>>(bmu, brho, alpha, beta, bnz,
                                              ascale, biasv, klacc);
    prep_w_kernel<<<2048, 256, 0, stream>>>(
        (const float4*)wmu, (const float4*)wrho, (const float4*)wnz,
        (f16x4*)W, klacc, OUT_F * IN_F / 4);
    prep_x_kernel<<<2048, 256, 0, stream>>>(
        (const float4*)x, (const float4*)du, (const float4*)ascale,
        (f16x4*)XD, BATCH * IN_F / 4);

    hipFuncSetAttribute((const void*)gemm_kernel,
                        hipFuncAttributeMaxDynamicSharedMemorySize, 131072);
    gemm_kernel<<<512, 512, 131072, stream>>>(XD, W, biasv, out);

    finalize_kernel<<<1, 1, 0, stream>>>(klacc, out + (size_t)BATCH * OUT_F);
}

// Round 8
// 361.165 us; speedup vs baseline: 1.0676x; 1.0210x over previous
//
#include <hip/hip_runtime.h>
#include <stdint.h>
#include <stddef.h>

#define IN_F  4096
#define OUT_F 4096
#define BATCH 8192

typedef _Float16 f16;
typedef _Float16 f16x4 __attribute__((ext_vector_type(4)));
typedef _Float16 f16x8 __attribute__((ext_vector_type(8)));
typedef float    f32x4 __attribute__((ext_vector_type(4)));

#define VMWAIT(n) asm volatile("s_waitcnt vmcnt(" #n ")" ::: "memory")
#define LGKM(n)   asm volatile("s_waitcnt lgkmcnt(" #n ")" ::: "memory")
#define BAR() do { asm volatile("" ::: "memory"); __builtin_amdgcn_s_barrier(); asm volatile("" ::: "memory"); } while (0)

// ---------------- helpers ----------------

__device__ __forceinline__ float softplus_f(float x) {
    // hw transcendentals only (log1pf is a slow software path); precision loss
    // ~1e-5 rel, KL threshold has 1e2x margin
    const float e = __expf(-fabsf(x));
    return fmaxf(x, 0.0f) + __logf(1.0f + e);
}

__device__ __forceinline__ void block_reduce_atomic(float v, float* dst) {
    #pragma unroll
    for (int off = 32; off > 0; off >>= 1) v += __shfl_down(v, off, 64);
    __shared__ float parts[16];
    const int lane = threadIdx.x & 63, wave = threadIdx.x >> 6;
    if (lane == 0) parts[wave] = v;
    __syncthreads();
    if (threadIdx.x == 0) {
        float s = 0.0f;
        const int nw = blockDim.x >> 6;
        for (int i = 0; i < nw; ++i) s += parts[i];
        atomicAdd(dst, s);
    }
}

__device__ __forceinline__ void async16(void* lds, const void* g) {
    __builtin_amdgcn_global_load_lds(
        (const __attribute__((address_space(1))) void*)g,
        (__attribute__((address_space(3))) void*)lds,
        16, 0, 0);
}

// ---------------- prep kernels ----------------

__global__ __launch_bounds__(256) void prep_w_kernel(
    const float4* __restrict__ mu4, const float4* __restrict__ rho4,
    const float4* __restrict__ nz4, f16x4* __restrict__ W4,
    float* __restrict__ kl_accum, int n4)
{
    float kl = 0.0f;
    const int stride = gridDim.x * blockDim.x;
    for (int i = blockIdx.x * blockDim.x + threadIdx.x; i < n4; i += stride) {
        const float4 m = mu4[i], r = rho4[i], z = nz4[i];
        const float mm[4] = {m.x, m.y, m.z, m.w};
        const float rr[4] = {r.x, r.y, r.z, r.w};
        const float zz[4] = {z.x, z.y, z.z, z.w};
        f16x4 w;
        #pragma unroll
        for (int c = 0; c < 4; ++c) {
            const float s = softplus_f(rr[c]);
            w[c] = (f16)(mm[c] + s * zz[c]);
            kl += 2.0f * __logf(s) + 1.0f / (s * s) + mm[c] * mm[c] - 1.0f;
        }
        W4[i] = w;
    }
    block_reduce_atomic(0.5f * kl, kl_accum);
}

__global__ __launch_bounds__(256) void prep_small_kernel(
    const float* __restrict__ bias_mu, const float* __restrict__ bias_rho,
    const float* __restrict__ alpha,   const float* __restrict__ beta,
    const float* __restrict__ bias_nz,
    float* __restrict__ ascale, float* __restrict__ bias,
    float* __restrict__ kl_accum)
{
    const int i = blockIdx.x * blockDim.x + threadIdx.x;
    float kl = 0.0f;
    if (i < IN_F) {
        const float sa = softplus_f(alpha[i]);
        const float sb = softplus_f(beta[i]);
        ascale[i] = sa * sb;
        kl += sa + sb - __logf(sa) - __logf(sb);
    }
    if (i < OUT_F) {
        const float s = softplus_f(bias_rho[i]);
        const float bm = bias_mu[i];
        bias[i] = bm + s * bias_nz[i];
        kl += 0.5f * (2.0f * __logf(s) + 1.0f / (s * s) + bm * bm - 1.0f);
    }
    block_reduce_atomic(kl, kl_accum);
}

__global__ __launch_bounds__(256) void prep_x_kernel(
    const float4* __restrict__ x4, const float4* __restrict__ u4,
    const float4* __restrict__ as4, f16x4* __restrict__ xd4, int n4)
{
    constexpr int C4 = IN_F / 4;
    const int stride = gridDim.x * blockDim.x;
    for (int i = blockIdx.x * blockDim.x + threadIdx.x; i < n4; i += stride) {
        const float4 xv = x4[i];
        const float4 uv = u4[i];
        const float4 av = as4[i & (C4 - 1)];
        f16x4 o;
        const float inv_keep = 1.0f / 0.9f;
        o[0] = (f16)((uv.x < 0.9f) ? xv.x * inv_keep * av.x : 0.0f);
        o[1] = (f16)((uv.y < 0.9f) ? xv.y * inv_keep * av.y : 0.0f);
        o[2] = (f16)((uv.z < 0.9f) ? xv.z * inv_keep * av.z : 0.0f);
        o[3] = (f16)((uv.w < 0.9f) ? xv.w * inv_keep * av.w : 0.0f);
        xd4[i] = o;
    }
}

// ---------------- GEMM: 256x256, BK=64, decoupled-phase counted-lgkm ----------------
// Reads of phase P feed the MFMA of phase P+1; pre-barrier wait is a COUNTED
// lgkmcnt(#reads issued this phase) -> drains only last phase's reads, so the
// post-barrier MFMA starts immediately while this phase's reads drain under it.
//   P0: stage B1(t+1) | read a_lo(t) |            lgkm(8) | BAR | q10(t-1)
//   P1: stage A0(t+1) | read b_lo(t) |            lgkm(4) | BAR | q11(t-1)
//   P2: stage A1(t+1) | read b_hi(t) | vmcnt(6) | lgkm(4) | BAR | q00(t)
//   P3: stage B0(t+2) | read a_hi(t) | vmcnt(4) | lgkm(8) | BAR | q01(t)
// Register liveness (R2-verified cycle): every MFMA operand read >=1 phase
// earlier, never reloaded before its last use. WAR: region R read at phase X
// drains at the counted lgkm of X+1 (pre-BAR); stage(R) issues >= phase X+2
// body (post-BAR(X+1)) -- checked per region. vmcnt FIFO (2 loads/half-region):
// entering-P0 invariant = {A1(t),B0(t+1)} = 4 outstanding; vmcnt(6)@P2 drains
// A1(t) for P3's read, vmcnt(4)@P3 drains A0(t+1) for P0(t+1)'s read and
// restores the invariant. Tail: stages wrap mod NT (never consumed), vmcnt(0)
// before epilogue.

#define QMFMA(MH, NH, AF, BF) do { \
    _Pragma("unroll") for (int mm_ = 0; mm_ < 4; ++mm_) \
    _Pragma("unroll") for (int nn_ = 0; nn_ < 2; ++nn_) \
    _Pragma("unroll") for (int ks_ = 0; ks_ < 2; ++ks_) \
        acc[(MH)*4+mm_][(NH)*2+nn_] = __builtin_amdgcn_mfma_f32_16x16x32_f16( \
            AF[mm_][ks_], BF[nn_][ks_], acc[(MH)*4+mm_][(NH)*2+nn_], 0, 0, 0); \
} while (0)

__global__ __launch_bounds__(512, 2) void gemm_kernel(
    const f16* __restrict__ A, const f16* __restrict__ B,
    const float* __restrict__ bias, float* __restrict__ C)
{
    constexpr int K = IN_F, N = OUT_F;
    constexpr int BK = 64, NT = K / BK; // 64 K-tiles

    extern __shared__ f16x8 smem_raw[];
    char* const smem = (char*)smem_raw;
    char* const sA = smem;          // [2 buf][2 half][128][64] f16, unit-swizzled
    char* const sB = smem + 65536;

    const int tid  = threadIdx.x;
    const int lane = tid & 63, wave = tid >> 6;
    const int wr = wave >> 2, wc = wave & 3;   // 2 x 4 waves
    const int fr = lane & 15, fq = lane >> 4;

    int bid = blockIdx.x;
    const int nbn = N / 256; // 16
    bid = (bid & 7) * 64 + (bid >> 3); // XCD swizzle, 512%8==0 bijective
    const int row0 = (bid / nbn) * 256, col0 = (bid % nbn) * 256;

    // staging source (pre-swizzled; linear gload_lds dest + swizzled ds_read)
    const int srow  = tid >> 3;
    const int sunit = (tid & 7) ^ (srow & 7);
    const f16* gA = A + (size_t)(row0 + srow) * K + sunit * 8;
    const f16* gB = B + (size_t)(col0 + srow) * K + sunit * 8;
    const int sdst = tid * 16;

#define STA(T, H, J) async16(sA + ((T) & 1) * 32768 + (H) * 16384 + (J) * 8192 + sdst, \
                             gA + (size_t)((H) * 128 + (J) * 64) * K + (T) * 64)
#define STB(T, H, J) async16(sB + ((T) & 1) * 32768 + (H) * 16384 + (J) * 8192 + sdst, \
                             gB + (size_t)((H) * 128 + (J) * 64) * K + (T) * 64)

    const int swz0 = (fq ^ (fr & 7)) << 4;
    const int arow = (wr * 16 + fr) * 128;
    const int brow = (wc * 16 + fr) * 128;

#define READ_ALO(buf) do { _Pragma("unroll") for (int mm = 0; mm < 4; ++mm) \
    _Pragma("unroll") for (int ks = 0; ks < 2; ++ks) \
        a_lo[mm][ks] = *(const f16x8*)(sA + (buf) + (((arow + mm * 4096) + swz0) ^ (ks << 6))); } while (0)
#define READ_AHI(buf) do { _Pragma("unroll") for (int mm = 0; mm < 4; ++mm) \
    _Pragma("unroll") for (int ks = 0; ks < 2; ++ks) \
        a_hi[mm][ks] = *(const f16x8*)(sA + (buf) + 16384 + (((arow + mm * 4096) + swz0) ^ (ks << 6))); } while (0)
#define READ_BLO(buf) do { _Pragma("unroll") for (int nn = 0; nn < 2; ++nn) \
    _Pragma("unroll") for (int ks = 0; ks < 2; ++ks) \
        b_lo[nn][ks] = *(const f16x8*)(sB + (buf) + (((brow + nn * 8192) + swz0) ^ (ks << 6))); } while (0)
#define READ_BHI(buf) do { _Pragma("unroll") for (int nn = 0; nn < 2; ++nn) \
    _Pragma("unroll") for (int ks = 0; ks < 2; ++ks) \
        b_hi[nn][ks] = *(const f16x8*)(sB + (buf) + 16384 + (((brow + nn * 8192) + swz0) ^ (ks << 6))); } while (0)

    f32x4 acc[8][4] = {};
    f16x8 a_lo[4][2], a_hi[4][2], b_lo[2][2], b_hi[2][2];

    // prologue: B0(0),B1(0),A0(0),A1(0),B0(1); vmcnt(4) leaves {A1(0),B0(1)}
    // = exact steady-state entering-P0 invariant. No prologue ds_reads.
    STB(0,0,0); STB(0,0,1);
    STB(0,1,0); STB(0,1,1);
    STA(0,0,0); STA(0,0,1);
    STA(0,1,0); STA(0,1,1);
    STB(1,0,0); STB(1,0,1);
    VMWAIT(4);
    BAR();

    for (int t = 0; t < NT; ++t) {
        const int bt  = (t & 1) * 32768;
        const int tp1 = (t + 1) & (NT - 1);
        const int tp2 = (t + 2) & (NT - 1);

        // ---- P0: stage B1(t+1) | read a_lo(t) | lgkm(8) | BAR | q10(t-1)
        STB(tp1, 1, 0); STB(tp1, 1, 1);
        READ_ALO(bt);
        LGKM(8);
        BAR();
        if (t > 0) {
            __builtin_amdgcn_s_setprio(1);
            QMFMA(1, 0, a_hi, b_lo);
            __builtin_amdgcn_s_setprio(0);
        }

        // ---- P1: stage A0(t+1) | read b_lo(t) | lgkm(4) | BAR | q11(t-1)
        STA(tp1, 0, 0); STA(tp1, 0, 1);
        READ_BLO(bt);
        LGKM(4);
        BAR();
        if (t > 0) {
            __builtin_amdgcn_s_setprio(1);
            QMFMA(1, 1, a_hi, b_hi);
            __builtin_amdgcn_s_setprio(0);
        }

        // ---- P2: stage A1(t+1) | read b_hi(t) | vmcnt(6) lgkm(4) | BAR | q00(t)
        STA(tp1, 1, 0); STA(tp1, 1, 1);
        READ_BHI(bt);
        VMWAIT(6);
        LGKM(4);
        BAR();
        __builtin_amdgcn_s_setprio(1);
        QMFMA(0, 0, a_lo, b_lo);
        __builtin_amdgcn_s_setprio(0);

        // ---- P3: stage B0(t+2) | read a_hi(t) | vmcnt(4) lgkm(8) | BAR | q01(t)
        STB(tp2, 0, 0); STB(tp2, 0, 1);
        READ_AHI(bt);
        VMWAIT(4);
        LGKM(8);
        BAR();
        __builtin_amdgcn_s_setprio(1);
        QMFMA(0, 1, a_lo, b_hi);
        __builtin_amdgcn_s_setprio(0);
    }
    // deferred quadrants of tile NT-1 (a_hi/b_lo/b_hi regs still live)
    QMFMA(1, 0, a_hi, b_lo);
    QMFMA(1, 1, a_hi, b_hi);
    VMWAIT(0);   // drain dangling wrapped stages

    // epilogue
    #pragma unroll
    for (int n = 0; n < 4; ++n) {
        const int col = col0 + n * 64 + wc * 16 + fr;
        const float bv = bias[col];
        #pragma unroll
        for (int m = 0; m < 8; ++m) {
            const int row = row0 + m * 32 + wr * 16 + fq * 4;
            #pragma unroll
            for (int r = 0; r < 4; ++r)
                C[(size_t)(row + r) * N + col] = acc[m][n][r] + bv;
        }
    }
#undef STA
#undef STB
}

__global__ void finalize_kernel(const float* __restrict__ kl, float* __restrict__ dst) {
    *dst = *kl;
}

// ---------------- launch ----------------

extern "C" void kernel_launch(void* const* d_in, const int* in_sizes, int n_in,
                              void* d_out, int out_size, void* d_ws, size_t ws_size,
                              hipStream_t stream)
{
    const float* x      = (const float*)d_in[0];
    const float* wmu    = (const float*)d_in[1];
    const float* wrho   = (const float*)d_in[2];
    const float* bmu    = (const float*)d_in[3];
    const float* brho   = (const float*)d_in[4];
    const float* alpha  = (const float*)d_in[5];
    const float* beta   = (const float*)d_in[6];
    const float* wnz    = (const float*)d_in[7];
    const float* bnz    = (const float*)d_in[8];
    const float* du     = (const float*)d_in[9];

    char* ws = (char*)d_ws;
    f16*   W      = (f16*)(ws);
    f16*   XD     = (f16*)(ws + 33554432);
    float* ascale = (float*)(ws + 100663296);
    float* biasv  = (float*)(ws + 100679680);
    float* klacc  = (float*)(ws + 100696064);

    float* out = (float*)d_out;

    hipMemsetAsync(klacc, 0, sizeof(float), stream);

    prep_small_kernel<<<16, 256, 0, stream>>>(bmu, brho, alpha, beta, bnz,
                                              ascale, biasv, klacc);
    prep_w_kernel<<<2048, 256, 0, stream>>>(
        (const float4*)wmu, (const float4*)wrho, (const float4*)wnz,
        (f16x4*)W, klacc, OUT_F * IN_F / 4);
    prep_x_kernel<<<2048, 256, 0, stream>>>(
        (const float4*)x, (const float4*)du, (const float4*)ascale,
        (f16x4*)XD, BATCH * IN_F / 4);

    hipFuncSetAttribute((const void*)gemm_kernel,
                        hipFuncAttributeMaxDynamicSharedMemorySize, 131072);
    gemm_kernel<<<512, 512, 131072, stream>>>(XD, W, biasv, out);

    finalize_kernel<<<1, 1, 0, stream>>>(klacc, out + (size_t)BATCH * OUT_F);
}